// Round 6
// baseline (282.824 us; speedup 1.0000x reference)
//
#include <hip/hip_runtime.h>

// Problem: B,H,W,D = 64,32,32,64 ; K=1024 ; N = 65536
#define NPTS   65536
#define DDIM   64
#define KCODES 1024
#define QOUT_ELEMS (NPTS * DDIM)

typedef _Float16 half8    __attribute__((ext_vector_type(8)));
typedef float    floatx16 __attribute__((ext_vector_type(16)));
typedef unsigned int uint;

#define AS1 __attribute__((address_space(1)))
#define AS3 __attribute__((address_space(3)))

// ws: ehp [0,128K) chunk-major f16 | elp [128K,256K) | e2 packed [256K,260K)
// scr: per-(point,kq) float2 candidates at 264K (2 MB)
#define WS_EHP   0
#define WS_ELP   (128*1024)
#define WS_E2    (256*1024)
#define WS_SCR   (264*1024)

union H8U { half8 v; uint u[4]; };

static __device__ __forceinline__ void gl_lds16(const void* g, void* l) {
    __builtin_amdgcn_global_load_lds((const AS1 uint*)g, (AS3 uint*)l, 16, 0, 0);
}

// ---------------------------------------------------------------------------
// Prep (verified r4/r5): one wave per code. fp16 hi/lo split, CHUNK-MAJOR:
// tile T=k>>5, chunk j=d>>3, c=k&31: byte off = T*4096 + j*512 + c*16 + (d&7)*2
// Plus packed (e2h,e2l) per code.
// ---------------------------------------------------------------------------
__global__ void eprep_kernel(const float* __restrict__ emb, char* __restrict__ ws) {
    const int tid = threadIdx.x;
    const int w = tid >> 6, d = tid & 63;
    const int k = blockIdx.x * 4 + w;
    float v = emb[(size_t)k * DDIM + d];
    _Float16 h = (_Float16)v;
    _Float16 l = (_Float16)(v - (float)h);
    size_t off = (size_t)(k >> 5) * 4096 + (size_t)(d >> 3) * 512
               + (size_t)(k & 31) * 16 + (size_t)(d & 7) * 2;
    *(_Float16*)(ws + WS_EHP + off) = h;
    *(_Float16*)(ws + WS_ELP + off) = l;
    float s = v * v;
    #pragma unroll
    for (int m = 1; m < 64; m <<= 1) s += __shfl_xor(s, m, 64);
    if (d == 0) {
        _Float16 e2h = (_Float16)s;
        _Float16 e2l = (_Float16)(s - (float)e2h);
        unsigned short hb = *(unsigned short*)&e2h;
        unsigned short lb = *(unsigned short*)&e2l;
        ((uint*)(ws + WS_E2))[k] = (uint)hb | ((uint)lb << 16);
    }
}

// ---------------------------------------------------------------------------
// Main: grid 1024 = (pgrp 256) x (kq 4). Block 256 thr = 4 waves.
// Wave w: M=64 points (two 32-pt sets, pgrp*256 + w*64 + set*32 + col) over its
// 256-code K-quarter (8 tiles of 32 = 4 double-buffered 2-tile steps).
// 4 blocks/CU by LDS; ~3 waves/SIMD by unified VGPR+AGPR (160 regs) -> the
// wave-level MFMA/VALU overlap r4/r5 lacked at 2 waves/SIMD.
// Layouts (verified r2/r4/r5): A[m][k]: m=lane&31,k=sel8*8+j; B same (n=lane&31);
// C/D: col=lane&31, row=(r&3)+8*(r>>2)+4*sel8.
// ---------------------------------------------------------------------------
__global__ __launch_bounds__(256, 3) void vq_kernel(
    const float* __restrict__ z,
    const char* __restrict__ ws_c,
    float2* __restrict__ scr)
{
    const int tid  = threadIdx.x;
    const int lane = tid & 63;
    const int w    = __builtin_amdgcn_readfirstlane(tid >> 6);
    const int col  = lane & 31;
    const int sel8 = lane >> 5;
    const int pgrp = blockIdx.x >> 2;
    const int kq   = blockIdx.x & 3;

    // double buffer: [buf][ eh q0 | eh q1 | el q0 | el q1 ] = 16 KB each
    __shared__ uint4 ldsbuf[2][1024];
    __shared__ uint  lds_e2[256];    // packed (e2h,e2l), this kq's 256 codes

    // ---- A fragments: a = -2 z[pt], hi/lo fp16, for both point sets ----
    half8 ah[2][4], al[2][4];
    #pragma unroll
    for (int set = 0; set < 2; ++set) {
        const int pt = pgrp * 256 + w * 64 + set * 32 + col;
        const float* zrow = z + (size_t)pt * DDIM + sel8 * 8;
        #pragma unroll
        for (int ks = 0; ks < 4; ++ks) {
            float4 u0 = *(const float4*)(zrow + ks * 16);
            float4 u1 = *(const float4*)(zrow + ks * 16 + 4);
            float tv[8] = {u0.x, u0.y, u0.z, u0.w, u1.x, u1.y, u1.z, u1.w};
            #pragma unroll
            for (int j = 0; j < 8; ++j) {
                float a = -2.0f * tv[j];
                _Float16 hh = (_Float16)a;
                ah[set][ks][j] = hh;
                al[set][ks][j] = (_Float16)(a - (float)hh);
            }
        }
    }
    // e2-step A: ones ONLY at k=0,1 (sel8==0 lanes) — r3 double-count fix.
    half8 ahE;
    { H8U t0; t0.u[0] = (sel8 == 0) ? 0x3C003C00u : 0u;
      t0.u[1] = t0.u[2] = t0.u[3] = 0u; ahE = t0.v; }

    // ---- prologue staging: e2 (wave 0, 1 KB) + step 0 tiles ----
    if (w == 0)
        gl_lds16(ws_c + WS_E2 + kq * 1024 + lane * 16, (char*)lds_e2);
    {
        const int opnd = w >> 1, q = w & 1;   // wave -> (eh/el, tile-in-step)
        const char* src = ws_c + (opnd ? WS_ELP : WS_EHP)
                        + (size_t)(kq * 8 + q) * 4096 + lane * 16;
        char* dst = (char*)ldsbuf[0] + (opnd * 8192 + q * 4096);
        #pragma unroll
        for (int i = 0; i < 4; ++i)
            gl_lds16(src + i * 1024, dst + i * 1024);
    }

    const floatx16 zeroC = {};
    float best[2][16];
    int   bt[2][16];
    #pragma unroll
    for (int set = 0; set < 2; ++set)
        #pragma unroll
        for (int r = 0; r < 16; ++r) { best[set][r] = 3.4e38f; bt[set][r] = 0; }

    for (int s = 0; s < 4; ++s) {
        __syncthreads();   // step-s stage landed; other buffer free
        if (s < 3) {       // prefetch step s+1 into the other buffer
            const int opnd = w >> 1, q = w & 1;
            const char* src = ws_c + (opnd ? WS_ELP : WS_EHP)
                            + (size_t)(kq * 8 + (s + 1) * 2 + q) * 4096 + lane * 16;
            char* dst = (char*)ldsbuf[(s + 1) & 1] + (opnd * 8192 + q * 4096);
            #pragma unroll
            for (int i = 0; i < 4; ++i)
                gl_lds16(src + i * 1024, dst + i * 1024);
        }
        const char* buf = (const char*)ldsbuf[s & 1];

        #pragma unroll
        for (int q = 0; q < 2; ++q) {
            const int tg = s * 2 + q;          // tile index within kq, 0..7
            const char* ehb = buf + q * 4096 + sel8 * 512 + col * 16;
            const char* elb = ehb + 8192;
            half8 bh[4], bl[4];
            #pragma unroll
            for (int ks = 0; ks < 4; ++ks) {
                bh[ks] = *(const half8*)(ehb + ks * 1024);
                bl[ks] = *(const half8*)(elb + ks * 1024);
            }
            half8 bhE;
            { H8U u; u.u[0] = lds_e2[tg * 32 + col];
              u.u[1] = u.u[2] = u.u[3] = 0u; bhE = u.v; }

            floatx16 a0, a1;   // two independent 13-MFMA chains (sets 0,1)
            a0 = __builtin_amdgcn_mfma_f32_32x32x16_f16(ah[0][0], bh[0], zeroC, 0, 0, 0);
            a1 = __builtin_amdgcn_mfma_f32_32x32x16_f16(ah[1][0], bh[0], zeroC, 0, 0, 0);
            a0 = __builtin_amdgcn_mfma_f32_32x32x16_f16(ah[0][1], bh[1], a0, 0, 0, 0);
            a1 = __builtin_amdgcn_mfma_f32_32x32x16_f16(ah[1][1], bh[1], a1, 0, 0, 0);
            a0 = __builtin_amdgcn_mfma_f32_32x32x16_f16(ah[0][2], bh[2], a0, 0, 0, 0);
            a1 = __builtin_amdgcn_mfma_f32_32x32x16_f16(ah[1][2], bh[2], a1, 0, 0, 0);
            a0 = __builtin_amdgcn_mfma_f32_32x32x16_f16(ah[0][3], bh[3], a0, 0, 0, 0);
            a1 = __builtin_amdgcn_mfma_f32_32x32x16_f16(ah[1][3], bh[3], a1, 0, 0, 0);
            a0 = __builtin_amdgcn_mfma_f32_32x32x16_f16(ahE, bhE, a0, 0, 0, 0);
            a1 = __builtin_amdgcn_mfma_f32_32x32x16_f16(ahE, bhE, a1, 0, 0, 0);
            a0 = __builtin_amdgcn_mfma_f32_32x32x16_f16(ah[0][0], bl[0], a0, 0, 0, 0);
            a1 = __builtin_amdgcn_mfma_f32_32x32x16_f16(ah[1][0], bl[0], a1, 0, 0, 0);
            a0 = __builtin_amdgcn_mfma_f32_32x32x16_f16(ah[0][1], bl[1], a0, 0, 0, 0);
            a1 = __builtin_amdgcn_mfma_f32_32x32x16_f16(ah[1][1], bl[1], a1, 0, 0, 0);
            a0 = __builtin_amdgcn_mfma_f32_32x32x16_f16(ah[0][2], bl[2], a0, 0, 0, 0);
            a1 = __builtin_amdgcn_mfma_f32_32x32x16_f16(ah[1][2], bl[2], a1, 0, 0, 0);
            a0 = __builtin_amdgcn_mfma_f32_32x32x16_f16(ah[0][3], bl[3], a0, 0, 0, 0);
            a1 = __builtin_amdgcn_mfma_f32_32x32x16_f16(ah[1][3], bl[3], a1, 0, 0, 0);
            a0 = __builtin_amdgcn_mfma_f32_32x32x16_f16(al[0][0], bh[0], a0, 0, 0, 0);
            a1 = __builtin_amdgcn_mfma_f32_32x32x16_f16(al[1][0], bh[0], a1, 0, 0, 0);
            a0 = __builtin_amdgcn_mfma_f32_32x32x16_f16(al[0][1], bh[1], a0, 0, 0, 0);
            a1 = __builtin_amdgcn_mfma_f32_32x32x16_f16(al[1][1], bh[1], a1, 0, 0, 0);
            a0 = __builtin_amdgcn_mfma_f32_32x32x16_f16(al[0][2], bh[2], a0, 0, 0, 0);
            a1 = __builtin_amdgcn_mfma_f32_32x32x16_f16(al[1][2], bh[2], a1, 0, 0, 0);
            a0 = __builtin_amdgcn_mfma_f32_32x32x16_f16(al[0][3], bh[3], a0, 0, 0, 0);
            a1 = __builtin_amdgcn_mfma_f32_32x32x16_f16(al[1][3], bh[3], a1, 0, 0, 0);

            #pragma unroll
            for (int r = 0; r < 16; ++r) {
                bool c0 = a0[r] < best[0][r];   // strict <: earliest tile on ties
                best[0][r] = c0 ? a0[r] : best[0][r];
                bt[0][r]   = c0 ? tg    : bt[0][r];
                bool c1 = a1[r] < best[1][r];
                best[1][r] = c1 ? a1[r] : best[1][r];
                bt[1][r]   = c1 ? tg    : bt[1][r];
            }
        }
    }

    // ---- per-set: codes, butterfly argmin over 32 cols, emit candidates ----
    #pragma unroll
    for (int set = 0; set < 2; ++set) {
        int code[16];
        #pragma unroll
        for (int r = 0; r < 16; ++r)
            code[r] = kq * 256 + bt[set][r] * 32 + col;
        #pragma unroll
        for (int m = 1; m < 32; m <<= 1) {
            #pragma unroll
            for (int r = 0; r < 16; ++r) {
                float ov = __shfl_xor(best[set][r], m, 64);
                int   oc = __shfl_xor(code[r], m, 64);
                bool c = (ov < best[set][r]) || (ov == best[set][r] && oc < code[r]);
                best[set][r] = c ? ov : best[set][r];
                code[r]      = c ? oc : code[r];
            }
        }
        if (col == 0) {   // lanes 0 / 32 hold rows (4*sel8 pattern)
            #pragma unroll
            for (int r = 0; r < 16; ++r) {
                int row = (r & 3) + 8 * (r >> 2) + 4 * sel8;
                int p = pgrp * 256 + w * 64 + set * 32 + row;
                scr[(size_t)p * 4 + kq] =
                    make_float2(best[set][r], __int_as_float(code[r]));
            }
        }
    }
}

// ---------------------------------------------------------------------------
// Merge the 4 kq candidates per point; gather quantized + write indices.
// kq ranges ascend in code: sequential strict-< keeps lowest code on ties.
// ---------------------------------------------------------------------------
__global__ void merge_gather_kernel(const float* __restrict__ emb,
                                    const float2* __restrict__ scr,
                                    float* __restrict__ out)
{
    int f = blockIdx.x * 256 + threadIdx.x;
    int pt = f >> 4, d4 = f & 15;
    float2 c0 = scr[(size_t)pt * 4];
    float bv = c0.x; int bi = __float_as_int(c0.y);
    #pragma unroll
    for (int j = 1; j < 4; ++j) {
        float2 cj = scr[(size_t)pt * 4 + j];
        if (cj.x < bv) { bv = cj.x; bi = __float_as_int(cj.y); }
    }
    ((float4*)out)[(size_t)pt * 16 + d4] = ((const float4*)emb)[(size_t)bi * 16 + d4];
    if (d4 == 0) out[QOUT_ELEMS + pt] = (float)bi;
}

extern "C" void kernel_launch(void* const* d_in, const int* in_sizes, int n_in,
                              void* d_out, int out_size, void* d_ws, size_t ws_size,
                              hipStream_t stream) {
    const float* z   = (const float*)d_in[0];
    const float* emb = (const float*)d_in[1];
    float* out = (float*)d_out;
    char* ws = (char*)d_ws;
    float2* scr = (float2*)(ws + WS_SCR);

    eprep_kernel<<<KCODES / 4, 256, 0, stream>>>(emb, ws);
    vq_kernel<<<1024, 256, 0, stream>>>(z, ws, scr);
    merge_gather_kernel<<<NPTS * 16 / 256, 256, 0, stream>>>(emb, scr, out);
}

// Round 7
// 117.957 us; speedup vs baseline: 2.3977x; 2.3977x over previous
//
#include <hip/hip_runtime.h>

// Problem: B,H,W,D = 64,32,32,64 ; K=1024 ; N = 65536
#define NPTS   65536
#define DDIM   64
#define KCODES 1024
#define QOUT_ELEMS (NPTS * DDIM)

typedef _Float16 half8    __attribute__((ext_vector_type(8)));
typedef float    floatx16 __attribute__((ext_vector_type(16)));
typedef unsigned int uint;

#define AS1 __attribute__((address_space(1)))
#define AS3 __attribute__((address_space(3)))

// ws: ehp [0,128K) chunk-major f16 | elp [128K,256K) | e2 packed [256K,260K)
// scr: per-(point,kq) float2 candidates at 264K (2 MB)
#define WS_EHP   0
#define WS_ELP   (128*1024)
#define WS_E2    (256*1024)
#define WS_SCR   (264*1024)

union H8U { half8 v; uint u[4]; };

static __device__ __forceinline__ void gl_lds16(const void* g, void* l) {
    __builtin_amdgcn_global_load_lds((const AS1 uint*)g, (AS3 uint*)l, 16, 0, 0);
}

// ---------------------------------------------------------------------------
// Prep (verified r4/r5): one wave per code. fp16 hi/lo split, CHUNK-MAJOR:
// tile T=k>>5, chunk j=d>>3, c=k&31: byte off = T*4096 + j*512 + c*16 + (d&7)*2
// Plus packed (e2h,e2l) per code.
// ---------------------------------------------------------------------------
__global__ void eprep_kernel(const float* __restrict__ emb, char* __restrict__ ws) {
    const int tid = threadIdx.x;
    const int w = tid >> 6, d = tid & 63;
    const int k = blockIdx.x * 4 + w;
    float v = emb[(size_t)k * DDIM + d];
    _Float16 h = (_Float16)v;
    _Float16 l = (_Float16)(v - (float)h);
    size_t off = (size_t)(k >> 5) * 4096 + (size_t)(d >> 3) * 512
               + (size_t)(k & 31) * 16 + (size_t)(d & 7) * 2;
    *(_Float16*)(ws + WS_EHP + off) = h;
    *(_Float16*)(ws + WS_ELP + off) = l;
    float s = v * v;
    #pragma unroll
    for (int m = 1; m < 64; m <<= 1) s += __shfl_xor(s, m, 64);
    if (d == 0) {
        _Float16 e2h = (_Float16)s;
        _Float16 e2l = (_Float16)(s - (float)e2h);
        unsigned short hb = *(unsigned short*)&e2h;
        unsigned short lb = *(unsigned short*)&e2l;
        ((uint*)(ws + WS_E2))[k] = (uint)hb | ((uint)lb << 16);
    }
}

// ---------------------------------------------------------------------------
// Main: grid 2048 = (pgrp 512) x (kq 4). Block 256 thr = 4 waves.
// Wave w: M=32 points (pgrp*128 + w*32 + col) over its 256-code K-quarter
// (8 tiles of 32 codes), single-tile double-buffer, one barrier per tile,
// prefetch issued one full compute-step (416 MFMA-cyc) ahead.
// SMALL per-wave reg footprint (~120 unified) — r6's spill came from forcing
// 3 waves/SIMD on an M=64 (~220-reg) working set; do NOT re-widen M.
// Layouts (verified r2/r4/r5): A[m][k]: m=lane&31,k=sel8*8+j; B same (n=lane&31);
// C/D: col=lane&31, row=(r&3)+8*(r>>2)+4*sel8.
// ---------------------------------------------------------------------------
__global__ __launch_bounds__(256, 3) void vq_kernel(
    const float* __restrict__ z,
    const char* __restrict__ ws_c,
    float2* __restrict__ scr)
{
    const int tid  = threadIdx.x;
    const int lane = tid & 63;
    const int w    = __builtin_amdgcn_readfirstlane(tid >> 6);
    const int col  = lane & 31;
    const int sel8 = lane >> 5;
    const int pgrp = blockIdx.x >> 2;
    const int kq   = blockIdx.x & 3;

    // double buffer: [buf][ eh 4KB | el 4KB ]
    __shared__ uint4 ldsbuf[2][512];
    __shared__ uint  lds_e2[256];    // packed (e2h,e2l), this kq's 256 codes

    // ---- A fragments: a = -2 z[pt], hi/lo fp16 ----
    const int pt = pgrp * 128 + w * 32 + col;
    half8 ah[4], al[4];
    {
        const float* zrow = z + (size_t)pt * DDIM + sel8 * 8;
        #pragma unroll
        for (int ks = 0; ks < 4; ++ks) {
            float4 u0 = *(const float4*)(zrow + ks * 16);
            float4 u1 = *(const float4*)(zrow + ks * 16 + 4);
            float tv[8] = {u0.x, u0.y, u0.z, u0.w, u1.x, u1.y, u1.z, u1.w};
            #pragma unroll
            for (int j = 0; j < 8; ++j) {
                float a = -2.0f * tv[j];
                _Float16 hh = (_Float16)a;
                ah[ks][j] = hh;
                al[ks][j] = (_Float16)(a - (float)hh);
            }
        }
    }
    // e2-step A: ones ONLY at k=0,1 (sel8==0 lanes) — r3 double-count fix.
    half8 ahE;
    { H8U t0; t0.u[0] = (sel8 == 0) ? 0x3C003C00u : 0u;
      t0.u[1] = t0.u[2] = t0.u[3] = 0u; ahE = t0.v; }

    // ---- prologue: e2 (wave 0, 1 KB) + tile 0 stage ----
    if (w == 0)
        gl_lds16(ws_c + WS_E2 + kq * 1024 + lane * 16, (char*)lds_e2);
    {
        const int opnd = w >> 1, hf = w & 1;   // wave -> (eh/el, 2KB half)
        const char* src = ws_c + (opnd ? WS_ELP : WS_EHP)
                        + (size_t)(kq * 8) * 4096 + hf * 2048 + lane * 16;
        char* dst = (char*)ldsbuf[0] + opnd * 4096 + hf * 2048;
        gl_lds16(src, dst);
        gl_lds16(src + 1024, dst + 1024);
    }

    const floatx16 zeroC = {};
    float best[16];
    int   bt[16];
    #pragma unroll
    for (int r = 0; r < 16; ++r) { best[r] = 3.4e38f; bt[r] = 0; }

    for (int t = 0; t < 8; ++t) {
        __syncthreads();   // tile-t stage landed (issued one full step ago)
        if (t < 7) {       // prefetch tile t+1 into the other buffer
            const int opnd = w >> 1, hf = w & 1;
            const char* src = ws_c + (opnd ? WS_ELP : WS_EHP)
                            + (size_t)(kq * 8 + t + 1) * 4096 + hf * 2048 + lane * 16;
            char* dst = (char*)ldsbuf[(t + 1) & 1] + opnd * 4096 + hf * 2048;
            gl_lds16(src, dst);
            gl_lds16(src + 1024, dst + 1024);
        }
        const char* buf = (const char*)ldsbuf[t & 1];
        const char* ehb = buf + sel8 * 512 + col * 16;
        const char* elb = ehb + 4096;
        half8 bh[4], bl[4];
        #pragma unroll
        for (int ks = 0; ks < 4; ++ks) {
            bh[ks] = *(const half8*)(ehb + ks * 1024);
            bl[ks] = *(const half8*)(elb + ks * 1024);
        }
        half8 bhE;
        { H8U u; u.u[0] = lds_e2[t * 32 + col];
          u.u[1] = u.u[2] = u.u[3] = 0u; bhE = u.v; }

        floatx16 acc;   // 13-MFMA chain: hh x4, e2, hl x4, lh x4
        acc = __builtin_amdgcn_mfma_f32_32x32x16_f16(ah[0], bh[0], zeroC, 0, 0, 0);
        acc = __builtin_amdgcn_mfma_f32_32x32x16_f16(ah[1], bh[1], acc, 0, 0, 0);
        acc = __builtin_amdgcn_mfma_f32_32x32x16_f16(ah[2], bh[2], acc, 0, 0, 0);
        acc = __builtin_amdgcn_mfma_f32_32x32x16_f16(ah[3], bh[3], acc, 0, 0, 0);
        acc = __builtin_amdgcn_mfma_f32_32x32x16_f16(ahE,  bhE,  acc, 0, 0, 0);
        acc = __builtin_amdgcn_mfma_f32_32x32x16_f16(ah[0], bl[0], acc, 0, 0, 0);
        acc = __builtin_amdgcn_mfma_f32_32x32x16_f16(ah[1], bl[1], acc, 0, 0, 0);
        acc = __builtin_amdgcn_mfma_f32_32x32x16_f16(ah[2], bl[2], acc, 0, 0, 0);
        acc = __builtin_amdgcn_mfma_f32_32x32x16_f16(ah[3], bl[3], acc, 0, 0, 0);
        acc = __builtin_amdgcn_mfma_f32_32x32x16_f16(al[0], bh[0], acc, 0, 0, 0);
        acc = __builtin_amdgcn_mfma_f32_32x32x16_f16(al[1], bh[1], acc, 0, 0, 0);
        acc = __builtin_amdgcn_mfma_f32_32x32x16_f16(al[2], bh[2], acc, 0, 0, 0);
        acc = __builtin_amdgcn_mfma_f32_32x32x16_f16(al[3], bh[3], acc, 0, 0, 0);

        #pragma unroll
        for (int r = 0; r < 16; ++r) {
            bool c = acc[r] < best[r];     // strict <: earliest tile wins ties
            best[r] = c ? acc[r] : best[r];
            bt[r]   = c ? t      : bt[r];
        }
    }

    // ---- codes; butterfly argmin over 32 cols; emit per-(point,kq) candidate ----
    int code[16];
    #pragma unroll
    for (int r = 0; r < 16; ++r) code[r] = kq * 256 + bt[r] * 32 + col;
    #pragma unroll
    for (int m = 1; m < 32; m <<= 1) {
        #pragma unroll
        for (int r = 0; r < 16; ++r) {
            float ov = __shfl_xor(best[r], m, 64);
            int   oc = __shfl_xor(code[r], m, 64);
            bool c = (ov < best[r]) || (ov == best[r] && oc < code[r]);
            best[r] = c ? ov : best[r];
            code[r] = c ? oc : code[r];
        }
    }
    if (col == 0) {   // lanes 0 / 32: 16 rows each
        #pragma unroll
        for (int r = 0; r < 16; ++r) {
            int row = (r & 3) + 8 * (r >> 2) + 4 * sel8;
            int p = pgrp * 128 + w * 32 + row;
            scr[(size_t)p * 4 + kq] = make_float2(best[r], __int_as_float(code[r]));
        }
    }
}

// ---------------------------------------------------------------------------
// Merge the 4 kq candidates per point; gather quantized + write indices.
// kq ranges ascend in code: sequential strict-< keeps lowest code on ties.
// ---------------------------------------------------------------------------
__global__ void merge_gather_kernel(const float* __restrict__ emb,
                                    const float2* __restrict__ scr,
                                    float* __restrict__ out)
{
    int f = blockIdx.x * 256 + threadIdx.x;
    int pt = f >> 4, d4 = f & 15;
    float2 c0 = scr[(size_t)pt * 4];
    float bv = c0.x; int bi = __float_as_int(c0.y);
    #pragma unroll
    for (int j = 1; j < 4; ++j) {
        float2 cj = scr[(size_t)pt * 4 + j];
        if (cj.x < bv) { bv = cj.x; bi = __float_as_int(cj.y); }
    }
    ((float4*)out)[(size_t)pt * 16 + d4] = ((const float4*)emb)[(size_t)bi * 16 + d4];
    if (d4 == 0) out[QOUT_ELEMS + pt] = (float)bi;
}

extern "C" void kernel_launch(void* const* d_in, const int* in_sizes, int n_in,
                              void* d_out, int out_size, void* d_ws, size_t ws_size,
                              hipStream_t stream) {
    const float* z   = (const float*)d_in[0];
    const float* emb = (const float*)d_in[1];
    float* out = (float*)d_out;
    char* ws = (char*)d_ws;
    float2* scr = (float2*)(ws + WS_SCR);

    eprep_kernel<<<KCODES / 4, 256, 0, stream>>>(emb, ws);
    vq_kernel<<<2048, 256, 0, stream>>>(z, ws, scr);
    merge_gather_kernel<<<NPTS * 16 / 256, 256, 0, stream>>>(emb, scr, out);
}

// Round 8
// 117.772 us; speedup vs baseline: 2.4015x; 1.0016x over previous
//
#include <hip/hip_runtime.h>

// Problem: B,H,W,D = 64,32,32,64 ; K=1024 ; N = 65536
#define NPTS   65536
#define DDIM   64
#define KCODES 1024
#define QOUT_ELEMS (NPTS * DDIM)

typedef _Float16 half8    __attribute__((ext_vector_type(8)));
typedef float    floatx16 __attribute__((ext_vector_type(16)));
typedef unsigned int uint;

#define AS1 __attribute__((address_space(1)))
#define AS3 __attribute__((address_space(3)))

// ws: eh [0,128K) chunk-major f16 | el [128K,256K) | e2 f32 [256K,260K)
//     zh [512K, 512K+8M) chunk-major f16 (-2z hi) | zl next 8M (-2z lo)
//     scr [pt][kg] float2 at 512K+16M (4 MB)
#define WS_EHP   0
#define WS_ELP   (128*1024)
#define WS_E2F   (256*1024)
#define WS_ZH    (512*1024)
#define WS_ZL    (WS_ZH + 8*1024*1024)
#define WS_SCR   (WS_ZH + 16*1024*1024)

static __device__ __forceinline__ void gl_lds16(const void* g, void* l) {
    __builtin_amdgcn_global_load_lds((const AS1 uint*)g, (AS3 uint*)l, 16, 0, 0);
}

// ---------------------------------------------------------------------------
// eprep: one wave per code. e -> f16 hi/lo chunk-major + ||e||^2 f32.
// chunk-major: tile T=k>>5, chunk j=d>>3, c=k&31: off = T*4096+j*512+c*16+(d&7)*2
// ---------------------------------------------------------------------------
__global__ void eprep_kernel(const float* __restrict__ emb, char* __restrict__ ws) {
    const int tid = threadIdx.x;
    const int w = tid >> 6, d = tid & 63;
    const int k = blockIdx.x * 4 + w;
    float v = emb[(size_t)k * DDIM + d];
    _Float16 h = (_Float16)v;
    _Float16 l = (_Float16)(v - (float)h);
    size_t off = (size_t)(k >> 5) * 4096 + (size_t)(d >> 3) * 512
               + (size_t)(k & 31) * 16 + (size_t)(d & 7) * 2;
    *(_Float16*)(ws + WS_EHP + off) = h;
    *(_Float16*)(ws + WS_ELP + off) = l;
    float s = v * v;
    #pragma unroll
    for (int m = 1; m < 64; m <<= 1) s += __shfl_xor(s, m, 64);
    if (d == 0) ((float*)(ws + WS_E2F))[k] = s;
}

// ---------------------------------------------------------------------------
// zprep: one wave per point. a = -2z -> f16 hi/lo chunk-major (by point-tile).
// ---------------------------------------------------------------------------
__global__ void zprep_kernel(const float* __restrict__ z, char* __restrict__ ws) {
    const int tid = threadIdx.x;
    const int w = tid >> 6, d = tid & 63;
    const int p = blockIdx.x * 4 + w;
    float a = -2.0f * z[(size_t)p * DDIM + d];
    _Float16 h = (_Float16)a;
    _Float16 l = (_Float16)(a - (float)h);
    size_t off = (size_t)(p >> 5) * 4096 + (size_t)(d >> 3) * 512
               + (size_t)(p & 31) * 16 + (size_t)(d & 7) * 2;
    *(_Float16*)(ws + WS_ZH + off) = h;
    *(_Float16*)(ws + WS_ZL + off) = l;
}

// ---------------------------------------------------------------------------
// Main (TRANSPOSED): grid 2048 = (pgrp 256) x (kg 8). Block 256 = 4 waves.
// Wave w owns 32 FIXED codes (kg*128 + w*32 + col) as A-frags; loops over 8
// point-tiles (B = -2z from LDS, dbuf staged, shared by all 4 waves).
// D[m=code][n=point]: col=lane&31 = point; row pattern = code. Per point the
// 32 code-scores sit in 16 regs x 2 half-waves: in-lane argmin (15 cmp) +
// ONE shfl-xor-32 — no 5-step butterfly (r7's LDS/VALU tax).
// e2 added as exact f32 (12 MFMAs/tile, no e2-MFMA).
// Per-tile 4-wave merge via 2KB LDS cand + rotating merger wave.
// ---------------------------------------------------------------------------
__global__ __launch_bounds__(256, 3) void vq_kernel(
    const char* __restrict__ ws_c,
    float2* __restrict__ scr)
{
    const int tid  = threadIdx.x;
    const int lane = tid & 63;
    const int w    = __builtin_amdgcn_readfirstlane(tid >> 6);
    const int col  = lane & 31;
    const int sel8 = lane >> 5;
    const int pgrp = blockIdx.x >> 3;
    const int kg   = blockIdx.x & 7;

    __shared__ uint4  zbuf[2][512];       // [buf][ zh 4KB | zl 4KB ]
    __shared__ float2 cand[2][4][32];     // [slot][wave][point-in-tile]

    // ---- A fragments: this wave's 32 codes (code-tile T = kg*4 + w) ----
    const char* eb = ws_c + WS_EHP + (size_t)(kg * 4 + w) * 4096 + sel8 * 512 + col * 16;
    half8 ah[4], al[4];
    #pragma unroll
    for (int ks = 0; ks < 4; ++ks) {
        ah[ks] = *(const half8*)(eb + ks * 1024);
        al[ks] = *(const half8*)(eb + (WS_ELP - WS_EHP) + ks * 1024);
    }
    // e2 per C-reg: row(r) = (r&3) + 8*(r>>2) + 4*sel8 (verified mapping)
    float e2r[16];
    {
        const float* e2f = (const float*)(ws_c + WS_E2F) + kg * 128 + w * 32 + 4 * sel8;
        #pragma unroll
        for (int r = 0; r < 16; ++r)
            e2r[r] = e2f[(r & 3) + 8 * (r >> 2)];
    }

    // ---- prologue: stage point-tile 0 (wave w: zh/zl half) ----
    {
        const int opnd = w >> 1, hf = w & 1;
        const char* src = ws_c + (opnd ? WS_ZL : WS_ZH)
                        + (size_t)(pgrp * 8) * 4096 + hf * 2048 + lane * 16;
        char* dst = (char*)zbuf[0] + opnd * 4096 + hf * 2048;
        gl_lds16(src, dst);
        gl_lds16(src + 1024, dst + 1024);
    }

    const floatx16 zeroC = {};

    for (int t = 0; t < 8; ++t) {
        __syncthreads();   // tile-t staged (issued one full step ago); cand[t-1] visible
        if (t < 7) {       // prefetch tile t+1 into other buffer
            const int opnd = w >> 1, hf = w & 1;
            const char* src = ws_c + (opnd ? WS_ZL : WS_ZH)
                            + (size_t)(pgrp * 8 + t + 1) * 4096 + hf * 2048 + lane * 16;
            char* dst = (char*)zbuf[(t + 1) & 1] + opnd * 4096 + hf * 2048;
            gl_lds16(src, dst);
            gl_lds16(src + 1024, dst + 1024);
        }
        // rotating merger: fold tile t-1's 4 wave-candidates, write scr
        if (t > 0 && w == ((t - 1) & 3) && lane < 32) {
            const int tt = t - 1;
            float2 c0 = cand[tt & 1][0][lane];
            float bvm = c0.x; int bim = __float_as_int(c0.y);
            #pragma unroll
            for (int j = 1; j < 4; ++j) {   // waves ascend in code: strict <
                float2 cj = cand[tt & 1][j][lane];
                bool c = cj.x < bvm;
                bvm = c ? cj.x : bvm;
                bim = c ? __float_as_int(cj.y) : bim;
            }
            int ptg = (pgrp * 8 + tt) * 32 + lane;
            scr[(size_t)ptg * 8 + kg] = make_float2(bvm, __int_as_float(bim));
        }

        // ---- B fragments: point-tile from LDS ----
        const char* zb = (const char*)zbuf[t & 1] + sel8 * 512 + col * 16;
        half8 bh[4], bl[4];
        #pragma unroll
        for (int ks = 0; ks < 4; ++ks) {
            bh[ks] = *(const half8*)(zb + ks * 1024);
            bl[ks] = *(const half8*)(zb + 4096 + ks * 1024);
        }

        floatx16 acc;   // 12-MFMA chain: hh x4, hl x4, lh x4
        acc = __builtin_amdgcn_mfma_f32_32x32x16_f16(ah[0], bh[0], zeroC, 0, 0, 0);
        acc = __builtin_amdgcn_mfma_f32_32x32x16_f16(ah[1], bh[1], acc, 0, 0, 0);
        acc = __builtin_amdgcn_mfma_f32_32x32x16_f16(ah[2], bh[2], acc, 0, 0, 0);
        acc = __builtin_amdgcn_mfma_f32_32x32x16_f16(ah[3], bh[3], acc, 0, 0, 0);
        acc = __builtin_amdgcn_mfma_f32_32x32x16_f16(ah[0], bl[0], acc, 0, 0, 0);
        acc = __builtin_amdgcn_mfma_f32_32x32x16_f16(ah[1], bl[1], acc, 0, 0, 0);
        acc = __builtin_amdgcn_mfma_f32_32x32x16_f16(ah[2], bl[2], acc, 0, 0, 0);
        acc = __builtin_amdgcn_mfma_f32_32x32x16_f16(ah[3], bl[3], acc, 0, 0, 0);
        acc = __builtin_amdgcn_mfma_f32_32x32x16_f16(al[0], bh[0], acc, 0, 0, 0);
        acc = __builtin_amdgcn_mfma_f32_32x32x16_f16(al[1], bh[1], acc, 0, 0, 0);
        acc = __builtin_amdgcn_mfma_f32_32x32x16_f16(al[2], bh[2], acc, 0, 0, 0);
        acc = __builtin_amdgcn_mfma_f32_32x32x16_f16(al[3], bh[3], acc, 0, 0, 0);

        // score = acc + e2 (exact f32); in-lane argmin over 16 rows (ascending)
        float sc[16];
        #pragma unroll
        for (int r = 0; r < 16; ++r) sc[r] = acc[r] + e2r[r];
        float bv = sc[0]; int br = 0;
        #pragma unroll
        for (int r = 1; r < 16; ++r) {
            bool c = sc[r] < bv;     // strict <: lowest row (code) wins ties
            bv = c ? sc[r] : bv;
            br = c ? r : br;
        }
        int bc = kg * 128 + w * 32 + (br & 3) + 8 * (br >> 2) + 4 * sel8;
        // merge the two half-wave code groups (interleaved rows: explicit tiebreak)
        float ov = __shfl_xor(bv, 32, 64);
        int   oc = __shfl_xor(bc, 32, 64);
        bool cm = (ov < bv) || (ov == bv && oc < bc);
        bv = cm ? ov : bv;
        bc = cm ? oc : bc;
        if (lane < 32) cand[t & 1][w][lane] = make_float2(bv, __int_as_float(bc));
    }

    __syncthreads();
    if (w == 3 && lane < 32) {   // merger for final tile (7&3 == 3)
        float2 c0 = cand[1][0][lane];
        float bvm = c0.x; int bim = __float_as_int(c0.y);
        #pragma unroll
        for (int j = 1; j < 4; ++j) {
            float2 cj = cand[1][j][lane];
            bool c = cj.x < bvm;
            bvm = c ? cj.x : bvm;
            bim = c ? __float_as_int(cj.y) : bim;
        }
        int ptg = (pgrp * 8 + 7) * 32 + lane;
        scr[(size_t)ptg * 8 + kg] = make_float2(bvm, __int_as_float(bim));
    }
}

// ---------------------------------------------------------------------------
// Merge the 8 kg candidates per point; gather quantized + write indices.
// Block = 16 points: threads 0-15 reduce, all 256 gather.
// ---------------------------------------------------------------------------
__global__ void merge_gather_kernel(const float* __restrict__ emb,
                                    const float2* __restrict__ scr,
                                    float* __restrict__ out)
{
    __shared__ int s_idx[16];
    const int tid = threadIdx.x;
    if (tid < 16) {
        int pt = blockIdx.x * 16 + tid;
        const float2* c = scr + (size_t)pt * 8;
        float bv = c[0].x; int bi = __float_as_int(c[0].y);
        #pragma unroll
        for (int j = 1; j < 8; ++j) {   // kg ascend in code: strict <
            float2 cj = c[j];
            bool cc = cj.x < bv;
            bv = cc ? cj.x : bv;
            bi = cc ? __float_as_int(cj.y) : bi;
        }
        s_idx[tid] = bi;
        out[QOUT_ELEMS + pt] = (float)bi;
    }
    __syncthreads();
    int p = tid >> 4, d4 = tid & 15;
    int ks = s_idx[p];
    ((float4*)out)[((size_t)blockIdx.x * 16 + p) * 16 + d4] =
        ((const float4*)emb)[(size_t)ks * 16 + d4];
}

extern "C" void kernel_launch(void* const* d_in, const int* in_sizes, int n_in,
                              void* d_out, int out_size, void* d_ws, size_t ws_size,
                              hipStream_t stream) {
    const float* z   = (const float*)d_in[0];
    const float* emb = (const float*)d_in[1];
    float* out = (float*)d_out;
    char* ws = (char*)d_ws;
    float2* scr = (float2*)(ws + WS_SCR);

    eprep_kernel<<<KCODES / 4, 256, 0, stream>>>(emb, ws);
    zprep_kernel<<<NPTS / 4, 256, 0, stream>>>(z, ws);
    vq_kernel<<<2048, 256, 0, stream>>>(ws, scr);
    merge_gather_kernel<<<NPTS / 16, 256, 0, stream>>>(emb, scr, out);
}